// Round 3
// baseline (341.491 us; speedup 1.0000x reference)
//
#include <hip/hip_runtime.h>

// Output layout (floats): pan [4,1,1024,1024] | lrms [4,4,256,256] | ms_up [4,4,1024,1024]
#define PAN_SZ  4194304
#define LRMS_OFF 4194304
#define MS_OFF  5242880

// ---------------------------------------------------------------------------
// K_eff[c][44][44] = (1/16) * sum_{di,dj in 0..3} mtf[c][p-di][q-dj]  (valid)
__global__ __launch_bounds__(256) void build_keff_kernel(
    const float* __restrict__ mtf, float* __restrict__ keff) {
  int e = blockIdx.x * 256 + threadIdx.x;
  if (e >= 4 * 44 * 44) return;
  int c = e / 1936;
  int rem = e - c * 1936;
  int p = rem / 44;
  int q = rem - p * 44;
  float s = 0.f;
  for (int di = 0; di < 4; ++di) {
    int u = p - di;
    if (u < 0 || u > 40) continue;
    for (int dj = 0; dj < 4; ++dj) {
      int v = q - dj;
      if (v < 0 || v > 40) continue;
      s += mtf[(c * 41 + u) * 41 + v];
    }
  }
  keff[e] = s * 0.0625f;
}

// ---------------------------------------------------------------------------
__global__ __launch_bounds__(256) void pan_kernel(
    const float* __restrict__ x, const float* __restrict__ w,
    float* __restrict__ pan) {
  int g = blockIdx.x * 256 + threadIdx.x;
  int b = g >> 18;
  int e = g & 262143;
  const float4* x4 = (const float4*)x;
  float w0 = w[0], w1 = w[1], w2 = w[2], w3 = w[3];
  float4 a0 = x4[(size_t)(b * 4 + 0) * 262144 + e];
  float4 a1 = x4[(size_t)(b * 4 + 1) * 262144 + e];
  float4 a2 = x4[(size_t)(b * 4 + 2) * 262144 + e];
  float4 a3 = x4[(size_t)(b * 4 + 3) * 262144 + e];
  float4 o;
  o.x = a0.x * w0 + a1.x * w1 + a2.x * w2 + a3.x * w3;
  o.y = a0.y * w0 + a1.y * w1 + a2.y * w2 + a3.y * w3;
  o.z = a0.z * w0 + a1.z * w1 + a2.z * w2 + a3.z * w3;
  o.w = a0.w * w0 + a1.w * w1 + a2.w * w2 + a3.w * w3;
  ((float4*)pan)[g] = o;
}

// ---------------------------------------------------------------------------
// lrms: stride-4 44x44 depthwise conv over edge-padded x (pool folded into K).
// NO LDS, NO barriers. Block = 4 waves = 4 column-quarters; lane owns 1 output
// col (oc = tid). Band of 8 output rows per block with rolling acc[8].
// Per staged input row: 11 coalesced float4 loads (register double-buffered);
// K rows are wave-uniform -> scalar loads (SGPR operand into v_fma).
__global__ __launch_bounds__(256) void lrms_kernel(
    const float* __restrict__ x, const float* __restrict__ keff,
    float* __restrict__ lrms) {
  int img = blockIdx.y;            // b*4 + ch
  int ch  = img & 3;
  int i0  = blockIdx.x * 8;        // band start output row
  int oc  = threadIdx.x;           // output col 0..255

  const float* ximg = x + (size_t)img * 1048576;
  const float* Kc   = keff + ch * 1936;

  float acc[8] = {0.f, 0.f, 0.f, 0.f, 0.f, 0.f, 0.f, 0.f};
  int c4base = oc - 5;                       // float4-col window start
  bool interior = (oc >= 5) && (oc <= 250);  // all 11 float4 in [0,255]

  float4 va[11], vb[11];

  auto loadrow = [&](int tt, float4* v) {
    int gy = 4 * i0 - 20 + tt;
    gy = gy < 0 ? 0 : (gy > 1023 ? 1023 : gy);
    const float4* row4 = (const float4*)(ximg + (size_t)gy * 1024);
    if (interior) {
      #pragma unroll
      for (int a = 0; a < 11; ++a) v[a] = row4[c4base + a];
    } else {
      const float* rowf = (const float*)row4;
      #pragma unroll
      for (int a = 0; a < 11; ++a) {
        int c4 = c4base + a;
        if ((unsigned)c4 <= 255u) {
          v[a] = row4[c4];
        } else {
          float4 t;
          t.x = rowf[min(max(4 * c4 + 0, 0), 1023)];
          t.y = rowf[min(max(4 * c4 + 1, 0), 1023)];
          t.z = rowf[min(max(4 * c4 + 2, 0), 1023)];
          t.w = rowf[min(max(4 * c4 + 3, 0), 1023)];
          v[a] = t;
        }
      }
    }
  };

  auto compute = [&](int tt, const float4* v) {
    #pragma unroll
    for (int r = 0; r < 8; ++r) {
      int p = tt - 4 * r;
      if ((unsigned)p < 44u) {
        // wave-uniform kernel row -> scalar loads
        const float* Kr = Kc + __builtin_amdgcn_readfirstlane(p * 44);
        float s = acc[r];
        #pragma unroll
        for (int a = 0; a < 11; ++a) {
          s += v[a].x * Kr[4 * a + 0] + v[a].y * Kr[4 * a + 1] +
               v[a].z * Kr[4 * a + 2] + v[a].w * Kr[4 * a + 3];
        }
        acc[r] = s;
      }
    }
  };

  // 72 staged input rows: tt = 0..71  (gy = 4*i0-20+tt, edge-clamped)
  loadrow(0, va);
  for (int it = 0; it < 36; ++it) {
    int tt = 2 * it;
    loadrow(tt + 1, vb);             // prefetch odd row
    compute(tt, va);
    if (tt + 2 < 72) loadrow(tt + 2, va);  // prefetch next even row
    compute(tt + 1, vb);
  }

  #pragma unroll
  for (int r = 0; r < 8; ++r)
    lrms[((size_t)img * 256 + i0 + r) * 256 + oc] = acc[r];
}

// ---------------------------------------------------------------------------
// Fused double x2 polyphase upsample (interp23tap, 2 stages), circular wrap.
__global__ __launch_bounds__(256) void interp_kernel(
    const float* __restrict__ lrms, const float* __restrict__ ik,
    float* __restrict__ ms) {
  __shared__ float lr[32][33];
  __shared__ float t1[32][44];
  __shared__ float s1[43][44];
  __shared__ float t2[43][64];
  __shared__ float k2[12];

  int img = blockIdx.z;
  int bx = blockIdx.x, by = blockIdx.y;
  int tid = threadIdx.x;

  if (tid < 12) k2[tid] = ik[2 * tid];

  const float* L = lrms + (size_t)img * 65536;
  int ybase = by * 16 - 8, xbase = bx * 16 - 8;
  for (int e = tid; e < 32 * 32; e += 256) {
    int yy = e >> 5, xx = e & 31;
    int gy = (ybase + yy) & 255;
    int gx = (xbase + xx) & 255;
    lr[yy][xx] = L[gy * 256 + gx];
  }
  __syncthreads();

  for (int e = tid; e < 32 * 43; e += 256) {
    int yy = e / 43, cc = e - yy * 43;
    float val;
    if ((cc & 1) == 0) {
      val = lr[yy][(cc >> 1) + 5];
    } else {
      int base = (cc - 5) >> 1;
      float s = 0.f;
      #pragma unroll
      for (int t = 0; t < 12; ++t) s += k2[t] * lr[yy][base + 2 + t];
      val = s;
    }
    t1[yy][cc] = val;
  }
  __syncthreads();

  for (int e = tid; e < 43 * 43; e += 256) {
    int rr = e / 43, cc = e - rr * 43;
    float val;
    if ((rr & 1) == 0) {
      val = t1[(rr >> 1) + 5][cc];
    } else {
      int base = (rr - 5) >> 1;
      float s = 0.f;
      #pragma unroll
      for (int t = 0; t < 12; ++t) s += k2[t] * t1[base + 2 + t][cc];
      val = s;
    }
    s1[rr][cc] = val;
  }
  __syncthreads();

  for (int e = tid; e < 43 * 64; e += 256) {
    int rr = e >> 6, mm = e & 63;
    float val;
    if ((mm & 1) == 0) {
      val = s1[rr][(mm >> 1) + 5];
    } else {
      int base = (mm - 1) >> 1;
      float s = 0.f;
      #pragma unroll
      for (int t = 0; t < 12; ++t) s += k2[t] * s1[rr][base + t];
      val = s;
    }
    t2[rr][mm] = val;
  }
  __syncthreads();

  float* O = ms + (size_t)img * 1048576 + (size_t)(by * 64) * 1024 + bx * 64;
  for (int e = tid; e < 64 * 64; e += 256) {
    int nn = e >> 6, mm = e & 63;
    float val;
    if ((nn & 1) == 0) {
      val = t2[(nn >> 1) + 5][mm];
    } else {
      int base = (nn - 1) >> 1;
      float s = 0.f;
      #pragma unroll
      for (int t = 0; t < 12; ++t) s += k2[t] * t2[base + t][mm];
      val = s;
    }
    O[(size_t)nn * 1024 + mm] = val;
  }
}

// ---------------------------------------------------------------------------
extern "C" void kernel_launch(void* const* d_in, const int* in_sizes, int n_in,
                              void* d_out, int out_size, void* d_ws, size_t ws_size,
                              hipStream_t stream) {
  const float* x   = (const float*)d_in[0];   // [4,4,1024,1024]
  const float* mtf = (const float*)d_in[1];   // [4,41,41]
  const float* ik  = (const float*)d_in[2];   // [23]
  const float* pw  = (const float*)d_in[3];   // [4]
  float* out = (float*)d_out;
  float* keff = (float*)d_ws;                 // 4*44*44 floats

  build_keff_kernel<<<31, 256, 0, stream>>>(mtf, keff);
  pan_kernel<<<4096, 256, 0, stream>>>(x, pw, out);
  lrms_kernel<<<dim3(32, 16), 256, 0, stream>>>(x, keff, out + LRMS_OFF);
  interp_kernel<<<dim3(16, 16, 16), 256, 0, stream>>>(out + LRMS_OFF, ik, out + MS_OFF);
}

// Round 4
// 330.236 us; speedup vs baseline: 1.0341x; 1.0341x over previous
//
#include <hip/hip_runtime.h>

// Output layout (floats): pan [4,1,1024,1024] | lrms [4,4,256,256] | ms_up [4,4,1024,1024]
#define LRMS_OFF 4194304
#define MS_OFF  5242880

// ---------------------------------------------------------------------------
// K_eff[c][44][44] = (1/16) * sum_{di,dj in 0..3} mtf[c][p-di][q-dj]  (valid)
__global__ __launch_bounds__(256) void build_keff_kernel(
    const float* __restrict__ mtf, float* __restrict__ keff) {
  int e = blockIdx.x * 256 + threadIdx.x;
  if (e >= 4 * 44 * 44) return;
  int c = e / 1936;
  int rem = e - c * 1936;
  int p = rem / 44;
  int q = rem - p * 44;
  float s = 0.f;
  for (int di = 0; di < 4; ++di) {
    int u = p - di;
    if (u < 0 || u > 40) continue;
    for (int dj = 0; dj < 4; ++dj) {
      int v = q - dj;
      if (v < 0 || v > 40) continue;
      s += mtf[(c * 41 + u) * 41 + v];
    }
  }
  keff[e] = s * 0.0625f;
}

// ---------------------------------------------------------------------------
// Composite x4 per-axis polyphase filters from the 23-tap interp kernel.
// k2[t] = ik[2t] (the 12 nonzero off-center taps). Phases of z[4i+d] on x:
//  d=0: z = sum_t k2[t] x[i+t-6]                        (12 taps, o in [-6,5])
//  d=2: z = x[i]                                         (1 tap)
//  d=1: direct t even: o=t/2-3; double t odd:  o=(t-5)/2 + r-6
//  d=3: direct t odd:  o=(t-5)/2; double t even: o=t/2 + r-8
// G[d][o+8], o in [-8,8].
__global__ void build_gcoef_kernel(const float* __restrict__ ik,
                                   float* __restrict__ G) {
  int tid = threadIdx.x;
  if (tid >= 68) return;
  int d = tid / 17, oi = tid % 17, o = oi - 8;
  float k2[12];
  #pragma unroll
  for (int t = 0; t < 12; ++t) k2[t] = ik[2 * t];
  float g = 0.f;
  if (d == 0) {
    int t = o + 6;
    if (t >= 0 && t < 12) g = k2[t];
  } else if (d == 2) {
    g = (o == 0) ? 1.f : 0.f;
  } else if (d == 1) {
    int t = 2 * (o + 3);
    if (t >= 0 && t <= 10) g += k2[t];
    for (int t1 = 1; t1 < 12; t1 += 2) {
      int r = o + 6 - (t1 - 5) / 2;
      if (r >= 0 && r < 12) g += k2[t1] * k2[r];
    }
  } else {  // d == 3
    int t = 2 * o + 5;
    if (t >= 1 && t <= 11) g += k2[t];
    for (int t0 = 0; t0 <= 10; t0 += 2) {
      int r = o + 8 - t0 / 2;
      if (r >= 0 && r < 12) g += k2[t0] * k2[r];
    }
  }
  G[d * 17 + oi] = g;
}

// ---------------------------------------------------------------------------
__global__ __launch_bounds__(256) void pan_kernel(
    const float* __restrict__ x, const float* __restrict__ w,
    float* __restrict__ pan) {
  int g = blockIdx.x * 256 + threadIdx.x;
  int b = g >> 18;
  int e = g & 262143;
  const float4* x4 = (const float4*)x;
  float w0 = w[0], w1 = w[1], w2 = w[2], w3 = w[3];
  float4 a0 = x4[(size_t)(b * 4 + 0) * 262144 + e];
  float4 a1 = x4[(size_t)(b * 4 + 1) * 262144 + e];
  float4 a2 = x4[(size_t)(b * 4 + 2) * 262144 + e];
  float4 a3 = x4[(size_t)(b * 4 + 3) * 262144 + e];
  float4 o;
  o.x = a0.x * w0 + a1.x * w1 + a2.x * w2 + a3.x * w3;
  o.y = a0.y * w0 + a1.y * w1 + a2.y * w2 + a3.y * w3;
  o.z = a0.z * w0 + a1.z * w1 + a2.z * w2 + a3.z * w3;
  o.w = a0.w * w0 + a1.w * w1 + a2.w * w2 + a3.w * w3;
  ((float4*)pan)[g] = o;
}

// ---------------------------------------------------------------------------
// lrms: stride-4 44x44 depthwise conv, pool folded into K. No LDS/barriers.
// Band of 4 output rows per block (grid 64x16 -> 4 waves/SIMD). float4
// partial-sum accumulators give 4 independent FMA chains per output row.
// K rows wave-uniform -> scalar (SGPR) loads feeding v_fmac directly.
__global__ __launch_bounds__(256) void lrms_kernel(
    const float* __restrict__ x, const float* __restrict__ keff,
    float* __restrict__ lrms) {
  int img = blockIdx.y;            // b*4 + ch
  int ch  = img & 3;
  int i0  = blockIdx.x * 4;        // band start output row
  int oc  = threadIdx.x;           // output col 0..255

  const float* ximg = x + (size_t)img * 1048576;
  const float* Kc   = keff + ch * 1936;

  float4 acc[4];
  #pragma unroll
  for (int r = 0; r < 4; ++r) acc[r] = make_float4(0.f, 0.f, 0.f, 0.f);

  int c4base = oc - 5;
  bool interior = (oc >= 5) && (oc <= 250);
  float4 va[11], vb[11];

  auto loadrow = [&](int tt, float4* v) {
    int gy = 4 * i0 - 20 + tt;
    gy = gy < 0 ? 0 : (gy > 1023 ? 1023 : gy);
    const float4* row4 = (const float4*)(ximg + (size_t)gy * 1024);
    if (interior) {
      #pragma unroll
      for (int a = 0; a < 11; ++a) v[a] = row4[c4base + a];
    } else {
      const float* rowf = (const float*)row4;
      #pragma unroll
      for (int a = 0; a < 11; ++a) {
        int c4 = c4base + a;
        if ((unsigned)c4 <= 255u) {
          v[a] = row4[c4];
        } else {
          float4 t;
          t.x = rowf[min(max(4 * c4 + 0, 0), 1023)];
          t.y = rowf[min(max(4 * c4 + 1, 0), 1023)];
          t.z = rowf[min(max(4 * c4 + 2, 0), 1023)];
          t.w = rowf[min(max(4 * c4 + 3, 0), 1023)];
          v[a] = t;
        }
      }
    }
  };

  auto compute = [&](int tt, const float4* v) {
    #pragma unroll
    for (int r = 0; r < 4; ++r) {
      int p = tt - 4 * r;
      if ((unsigned)p < 44u) {
        const float* Kr = Kc + __builtin_amdgcn_readfirstlane(p * 44);
        float4 s = acc[r];
        #pragma unroll
        for (int a = 0; a < 11; ++a) {
          s.x += v[a].x * Kr[4 * a + 0];
          s.y += v[a].y * Kr[4 * a + 1];
          s.z += v[a].z * Kr[4 * a + 2];
          s.w += v[a].w * Kr[4 * a + 3];
        }
        acc[r] = s;
      }
    }
  };

  // 56 staged input rows (gy = 4*i0-20+tt, edge-clamped), double-buffered
  loadrow(0, va);
  for (int it = 0; it < 28; ++it) {
    int tt = 2 * it;
    loadrow(tt + 1, vb);
    compute(tt, va);
    if (tt + 2 < 56) loadrow(tt + 2, va);
    compute(tt + 1, vb);
  }

  #pragma unroll
  for (int r = 0; r < 4; ++r) {
    float s = acc[r].x + acc[r].y + acc[r].z + acc[r].w;
    lrms[((size_t)img * 256 + i0 + r) * 256 + oc] = s;
  }
}

// ---------------------------------------------------------------------------
// Fused x4 upsample via composed polyphase filters. Block: 16x16 lrms tile
// (+/-8 circular halo) -> H pass (horizontal, 4 phases/thread share 17 LDS
// reads) -> V pass -> 64x64 output tile. 2 barriers, no divisions.
__global__ __launch_bounds__(256) void interp_kernel(
    const float* __restrict__ lrms, const float* __restrict__ G,
    float* __restrict__ ms) {
  __shared__ float lr[32][48];   // stride 48 -> <=2-way banks on H-pass reads
  __shared__ float H[32][68];    // stride 68 (16B aligned for float4 writes)
  __shared__ float Gs[4][17];

  int img = blockIdx.z;
  int bx = blockIdx.x, by = blockIdx.y;
  int tid = threadIdx.x;

  if (tid < 68) Gs[tid / 17][tid % 17] = G[tid];

  const float* L = lrms + (size_t)img * 65536;
  int ybase = by * 16 - 8, xbase = bx * 16 - 8;
  for (int e = tid; e < 1024; e += 256) {
    int yy = e >> 5, xx = e & 31;
    lr[yy][xx] = L[((ybase + yy) & 255) * 256 + ((xbase + xx) & 255)];
  }
  __syncthreads();

  // H pass: 32 rows x 16 jloc; each unit emits float4 (dx = 0..3)
  for (int u = tid; u < 512; u += 256) {
    int r = u >> 4, j = u & 15;
    float t[17];
    #pragma unroll
    for (int o = 0; o < 17; ++o) t[o] = lr[r][j + o];
    float h0 = 0.f, h1 = 0.f, h3 = 0.f;
    #pragma unroll
    for (int o = 2; o <= 13; ++o) h0 += Gs[0][o] * t[o];
    #pragma unroll
    for (int o = 0; o < 17; ++o) h1 += Gs[1][o] * t[o];
    #pragma unroll
    for (int o = 0; o < 17; ++o) h3 += Gs[3][o] * t[o];
    float4 hv = make_float4(h0, h1, t[8], h3);
    *(float4*)(&H[r][4 * j]) = hv;
  }
  __syncthreads();

  // V pass: 16 iloc x 64 X; each unit emits 4 output rows (dy = 0..3)
  float* O = ms + (size_t)img * 1048576 + (size_t)(by * 64) * 1024 + bx * 64;
  for (int u = tid; u < 1024; u += 256) {
    int il = u >> 6, X = u & 63;
    float t[17];
    #pragma unroll
    for (int o = 0; o < 17; ++o) t[o] = H[il + o][X];
    float v0 = 0.f, v1 = 0.f, v3 = 0.f;
    #pragma unroll
    for (int o = 2; o <= 13; ++o) v0 += Gs[0][o] * t[o];
    #pragma unroll
    for (int o = 0; o < 17; ++o) v1 += Gs[1][o] * t[o];
    #pragma unroll
    for (int o = 0; o < 17; ++o) v3 += Gs[3][o] * t[o];
    O[(size_t)(4 * il + 0) * 1024 + X] = v0;
    O[(size_t)(4 * il + 1) * 1024 + X] = v1;
    O[(size_t)(4 * il + 2) * 1024 + X] = t[8];
    O[(size_t)(4 * il + 3) * 1024 + X] = v3;
  }
}

// ---------------------------------------------------------------------------
extern "C" void kernel_launch(void* const* d_in, const int* in_sizes, int n_in,
                              void* d_out, int out_size, void* d_ws, size_t ws_size,
                              hipStream_t stream) {
  const float* x   = (const float*)d_in[0];   // [4,4,1024,1024]
  const float* mtf = (const float*)d_in[1];   // [4,41,41]
  const float* ik  = (const float*)d_in[2];   // [23]
  const float* pw  = (const float*)d_in[3];   // [4]
  float* out = (float*)d_out;
  float* keff = (float*)d_ws;                 // 4*44*44 = 7744 floats
  float* G    = keff + 7744;                  // 4*17 floats

  build_keff_kernel<<<31, 256, 0, stream>>>(mtf, keff);
  build_gcoef_kernel<<<1, 128, 0, stream>>>(ik, G);
  pan_kernel<<<4096, 256, 0, stream>>>(x, pw, out);
  lrms_kernel<<<dim3(64, 16), 256, 0, stream>>>(x, keff, out + LRMS_OFF);
  interp_kernel<<<dim3(16, 16, 16), 256, 0, stream>>>(out + LRMS_OFF, G, out + MS_OFF);
}

// Round 5
// 290.124 us; speedup vs baseline: 1.1771x; 1.1383x over previous
//
#include <hip/hip_runtime.h>

// Output layout (floats): pan [4,1,1024,1024] | lrms [4,4,256,256] | ms_up [4,4,1024,1024]
#define LRMS_OFF 4194304
#define MS_OFF  5242880

// ---------------------------------------------------------------------------
// Blocks 0..30: K_eff[c][44][44] = (1/16) * (mtf conv box4)   (pool folded in)
// Block 31:     composite x4 per-axis polyphase filters G[4][17] from ik.
__global__ __launch_bounds__(256) void build_coefs_kernel(
    const float* __restrict__ mtf, const float* __restrict__ ik,
    float* __restrict__ keff, float* __restrict__ G) {
  if (blockIdx.x < 31) {
    int e = blockIdx.x * 256 + threadIdx.x;
    if (e >= 4 * 44 * 44) return;
    int c = e / 1936;
    int rem = e - c * 1936;
    int p = rem / 44;
    int q = rem - p * 44;
    float s = 0.f;
    for (int di = 0; di < 4; ++di) {
      int u = p - di;
      if (u < 0 || u > 40) continue;
      for (int dj = 0; dj < 4; ++dj) {
        int v = q - dj;
        if (v < 0 || v > 40) continue;
        s += mtf[(c * 41 + u) * 41 + v];
      }
    }
    keff[e] = s * 0.0625f;
  } else {
    int tid = threadIdx.x;
    if (tid >= 68) return;
    int d = tid / 17, oi = tid % 17, o = oi - 8;
    float k2[12];
    #pragma unroll
    for (int t = 0; t < 12; ++t) k2[t] = ik[2 * t];
    float g = 0.f;
    if (d == 0) {
      int t = o + 6;
      if (t >= 0 && t < 12) g = k2[t];
    } else if (d == 2) {
      g = (o == 0) ? 1.f : 0.f;
    } else if (d == 1) {
      int t = 2 * (o + 3);
      if (t >= 0 && t <= 10) g += k2[t];
      for (int t1 = 1; t1 < 12; t1 += 2) {
        int r = o + 6 - (t1 - 5) / 2;
        if (r >= 0 && r < 12) g += k2[t1] * k2[r];
      }
    } else {  // d == 3
      int t = 2 * o + 5;
      if (t >= 1 && t <= 11) g += k2[t];
      for (int t0 = 0; t0 <= 10; t0 += 2) {
        int r = o + 8 - t0 / 2;
        if (r >= 0 && r < 12) g += k2[t0] * k2[r];
      }
    }
    G[d * 17 + oi] = g;
  }
}

// ---------------------------------------------------------------------------
__global__ __launch_bounds__(256) void pan_kernel(
    const float* __restrict__ x, const float* __restrict__ w,
    float* __restrict__ pan) {
  int g = blockIdx.x * 256 + threadIdx.x;
  int b = g >> 18;
  int e = g & 262143;
  const float4* x4 = (const float4*)x;
  float w0 = w[0], w1 = w[1], w2 = w[2], w3 = w[3];
  float4 a0 = x4[(size_t)(b * 4 + 0) * 262144 + e];
  float4 a1 = x4[(size_t)(b * 4 + 1) * 262144 + e];
  float4 a2 = x4[(size_t)(b * 4 + 2) * 262144 + e];
  float4 a3 = x4[(size_t)(b * 4 + 3) * 262144 + e];
  float4 o;
  o.x = a0.x * w0 + a1.x * w1 + a2.x * w2 + a3.x * w3;
  o.y = a0.y * w0 + a1.y * w1 + a2.y * w2 + a3.y * w3;
  o.z = a0.z * w0 + a1.z * w1 + a2.z * w2 + a3.z * w3;
  o.w = a0.w * w0 + a1.w * w1 + a2.w * w2 + a3.w * w3;
  ((float4*)pan)[g] = o;
}

// ---------------------------------------------------------------------------
// lrms: stride-4 44x44 depthwise conv (pool folded into K). No LDS/barriers.
// Lane owns 4 output cols (16 floats of x per staged row -> 14 float4 window);
// each wave rolls 4 adjacent output rows: acc[4][4] = 16 independent chains.
// One register window feeds up to 704 FMAs. K rows wave-uniform -> s_loads.
// Edge cols: windows are float4-aligned & fully in/out -> clamp idx + splat.
__global__ __launch_bounds__(256, 1) void lrms_kernel(
    const float* __restrict__ x, const float* __restrict__ keff,
    float* __restrict__ lrms) {
  int img = blockIdx.y;            // b*4 + ch
  int ch  = img & 3;
  int w   = threadIdx.x >> 6;      // wave id 0..3
  int lane = threadIdx.x & 63;
  int I0  = blockIdx.x * 16 + w * 4;  // this wave's first output row

  const float* ximg = x + (size_t)img * 1048576;
  const float* Kc   = keff + ch * 1936;

  float acc[4][4];
  #pragma unroll
  for (int r = 0; r < 4; ++r)
    #pragma unroll
    for (int c = 0; c < 4; ++c) acc[r][c] = 0.f;

  int c4base = 4 * lane - 5;       // window float4 index for j=0
  float4 Wa[14], Wb[14];

  auto loadrow = [&](int tt, float4* W) {
    int gy = 4 * I0 - 20 + tt;
    gy = gy < 0 ? 0 : (gy > 1023 ? 1023 : gy);
    const float4* row4 = (const float4*)(ximg + (size_t)gy * 1024);
    #pragma unroll
    for (int j = 0; j < 14; ++j) {
      int idx = c4base + j;
      int ic = idx < 0 ? 0 : (idx > 255 ? 255 : idx);
      float4 t = row4[ic];
      if (j <= 4) {                 // only lanes 0..1 can be left-OOB
        if (idx < 0) t = make_float4(t.x, t.x, t.x, t.x);
      }
      if (j >= 9) {                 // only lanes 62..63 can be right-OOB
        if (idx > 255) t = make_float4(t.w, t.w, t.w, t.w);
      }
      W[j] = t;
    }
  };

  auto compute = [&](int tt, const float4* W) {
    #pragma unroll
    for (int r = 0; r < 4; ++r) {
      int p = tt - 4 * r;
      if ((unsigned)p < 44u) {
        const float* Kr = Kc + __builtin_amdgcn_readfirstlane(p * 44);
        #pragma unroll
        for (int a = 0; a < 11; ++a) {
          float k0 = Kr[4 * a + 0], k1 = Kr[4 * a + 1];
          float k2 = Kr[4 * a + 2], k3 = Kr[4 * a + 3];
          #pragma unroll
          for (int c = 0; c < 4; ++c) {
            float4 v = W[c + a];
            acc[r][c] += v.x * k0 + v.y * k1 + v.z * k2 + v.w * k3;
          }
        }
      }
    }
  };

  // 56 staged input rows (gy = 4*I0-20+tt, edge-clamped), double-buffered
  loadrow(0, Wa);
  for (int tt = 0; tt < 56; tt += 2) {
    loadrow(tt + 1, Wb);
    compute(tt, Wa);
    if (tt + 2 < 56) loadrow(tt + 2, Wa);
    compute(tt + 1, Wb);
  }

  #pragma unroll
  for (int r = 0; r < 4; ++r) {
    float4 res = make_float4(acc[r][0], acc[r][1], acc[r][2], acc[r][3]);
    ((float4*)lrms)[((size_t)img * 256 + I0 + r) * 64 + lane] = res;
  }
}

// ---------------------------------------------------------------------------
// Fused x4 upsample via composed polyphase filters. Block: 16x16 lrms tile
// (+/-8 circular halo) -> H pass -> V pass -> 64x64 output tile. 2 barriers.
__global__ __launch_bounds__(256) void interp_kernel(
    const float* __restrict__ lrms, const float* __restrict__ G,
    float* __restrict__ ms) {
  __shared__ float lr[32][48];
  __shared__ float H[32][68];
  __shared__ float Gs[4][17];

  int img = blockIdx.z;
  int bx = blockIdx.x, by = blockIdx.y;
  int tid = threadIdx.x;

  if (tid < 68) Gs[tid / 17][tid % 17] = G[tid];

  const float* L = lrms + (size_t)img * 65536;
  int ybase = by * 16 - 8, xbase = bx * 16 - 8;
  for (int e = tid; e < 1024; e += 256) {
    int yy = e >> 5, xx = e & 31;
    lr[yy][xx] = L[((ybase + yy) & 255) * 256 + ((xbase + xx) & 255)];
  }
  __syncthreads();

  // H pass: 32 rows x 16 jloc; each unit emits float4 (dx = 0..3)
  for (int u = tid; u < 512; u += 256) {
    int r = u >> 4, j = u & 15;
    float t[17];
    #pragma unroll
    for (int o = 0; o < 17; ++o) t[o] = lr[r][j + o];
    float h0 = 0.f, h1 = 0.f, h3 = 0.f;
    #pragma unroll
    for (int o = 2; o <= 13; ++o) h0 += Gs[0][o] * t[o];
    #pragma unroll
    for (int o = 0; o < 17; ++o) h1 += Gs[1][o] * t[o];
    #pragma unroll
    for (int o = 0; o < 17; ++o) h3 += Gs[3][o] * t[o];
    *(float4*)(&H[r][4 * j]) = make_float4(h0, h1, t[8], h3);
  }
  __syncthreads();

  // V pass: 16 iloc x 64 X; each unit emits 4 output rows (dy = 0..3)
  float* O = ms + (size_t)img * 1048576 + (size_t)(by * 64) * 1024 + bx * 64;
  for (int u = tid; u < 1024; u += 256) {
    int il = u >> 6, X = u & 63;
    float t[17];
    #pragma unroll
    for (int o = 0; o < 17; ++o) t[o] = H[il + o][X];
    float v0 = 0.f, v1 = 0.f, v3 = 0.f;
    #pragma unroll
    for (int o = 2; o <= 13; ++o) v0 += Gs[0][o] * t[o];
    #pragma unroll
    for (int o = 0; o < 17; ++o) v1 += Gs[1][o] * t[o];
    #pragma unroll
    for (int o = 0; o < 17; ++o) v3 += Gs[3][o] * t[o];
    O[(size_t)(4 * il + 0) * 1024 + X] = v0;
    O[(size_t)(4 * il + 1) * 1024 + X] = v1;
    O[(size_t)(4 * il + 2) * 1024 + X] = t[8];
    O[(size_t)(4 * il + 3) * 1024 + X] = v3;
  }
}

// ---------------------------------------------------------------------------
extern "C" void kernel_launch(void* const* d_in, const int* in_sizes, int n_in,
                              void* d_out, int out_size, void* d_ws, size_t ws_size,
                              hipStream_t stream) {
  const float* x   = (const float*)d_in[0];   // [4,4,1024,1024]
  const float* mtf = (const float*)d_in[1];   // [4,41,41]
  const float* ik  = (const float*)d_in[2];   // [23]
  const float* pw  = (const float*)d_in[3];   // [4]
  float* out = (float*)d_out;
  float* keff = (float*)d_ws;                 // 4*44*44 = 7744 floats
  float* G    = keff + 7744;                  // 4*17 floats

  build_coefs_kernel<<<32, 256, 0, stream>>>(mtf, ik, keff, G);
  pan_kernel<<<4096, 256, 0, stream>>>(x, pw, out);
  lrms_kernel<<<dim3(16, 16), 256, 0, stream>>>(x, keff, out + LRMS_OFF);
  interp_kernel<<<dim3(16, 16, 16), 256, 0, stream>>>(out + LRMS_OFF, G, out + MS_OFF);
}